// Round 1
// baseline (1428.422 us; speedup 1.0000x reference)
//
#include <hip/hip_runtime.h>
#include <math.h>

#define BB   32      // batch
#define NN   1024    // nodes
#define DIN  2
#define DOUT 64
#define CIN  66      // DIN + DOUT
#define TD   32
#define ED   10
#define OG   128     // 2*DOUT (gate out)
#define OU   64      // upd out

// ---------------------------------------------------------------------------
// helper: X[b,m,c] on the fly. MODE 0: ins = concat(x,state). MODE 1: cand =
// concat(x, z*state) with z = zr[...,:64].
// ---------------------------------------------------------------------------
template<int MODE>
__device__ __forceinline__ float loadX(const float* __restrict__ x,
                                       const float* __restrict__ state,
                                       const float* __restrict__ zr,
                                       int b, int m, int c)
{
    if (c < DIN) return x[((size_t)b*NN + m)*DIN + c];
    int j = c - DIN;
    float s = state[((size_t)b*NN + m)*DOUT + j];
    if (MODE == 1) s *= zr[((size_t)b*NN + m)*OG + j];
    return s;
}

// ---------------------------------------------------------------------------
// K1: tiny MLPs -> nv1, nv2  (one thread per (b,n) point)
// ---------------------------------------------------------------------------
__global__ __launch_bounds__(256) void k_nv(
    const float* __restrict__ x, const float* __restrict__ state,
    const float* __restrict__ ne0, const float* __restrict__ ne1,
    const float* __restrict__ w11, const float* __restrict__ b11,
    const float* __restrict__ w12, const float* __restrict__ b12,
    const float* __restrict__ w13, const float* __restrict__ b13,
    const float* __restrict__ w21, const float* __restrict__ b21,
    const float* __restrict__ w22, const float* __restrict__ b22,
    const float* __restrict__ w23, const float* __restrict__ b23,
    float* __restrict__ nv1, float* __restrict__ nv2)
{
    const int oW1 = 0, oB1 = 1056, oW2 = 1072, oB2 = 1104, oW3 = 1108, oB3 = 1172, F2 = 1204;
    __shared__ float sw[2408];
    int t = threadIdx.x;
    for (int i = t; i < 1056; i += 256) { sw[oW1+i] = w11[i]; sw[F2+oW1+i] = w21[i]; }
    if (t < 16) { sw[oB1+t] = b11[t]; sw[F2+oB1+t] = b21[t]; }
    if (t < 32) { sw[oW2+t] = w12[t]; sw[F2+oW2+t] = w22[t]; }
    if (t < 2)  { sw[oB2+t] = b12[t]; sw[F2+oB2+t] = b22[t]; }
    if (t < 64) { sw[oW3+t] = w13[t]; sw[F2+oW3+t] = w23[t]; }
    if (t >= 64 && t < 96) { sw[oB3+t-64] = b13[t-64]; sw[F2+oB3+t-64] = b23[t-64]; }
    __syncthreads();

    int p = blockIdx.x*256 + t;
    int b = p >> 10;                         // N = 1024

    float h1a[16], h1b[16];
    #pragma unroll
    for (int j = 0; j < 16; ++j) { h1a[j] = sw[oB1+j]; h1b[j] = sw[F2+oB1+j]; }
    for (int i = 0; i < CIN; ++i) {
        float v = (i < DIN) ? x[(size_t)p*DIN + i] : state[(size_t)p*DOUT + (i-DIN)];
        #pragma unroll
        for (int jq = 0; jq < 4; ++jq) {
            float4 wa = *(const float4*)&sw[oW1 + i*16 + jq*4];
            float4 wb = *(const float4*)&sw[F2 + oW1 + i*16 + jq*4];
            h1a[jq*4+0] += v*wa.x; h1a[jq*4+1] += v*wa.y;
            h1a[jq*4+2] += v*wa.z; h1a[jq*4+3] += v*wa.w;
            h1b[jq*4+0] += v*wb.x; h1b[jq*4+1] += v*wb.y;
            h1b[jq*4+2] += v*wb.z; h1b[jq*4+3] += v*wb.w;
        }
    }
    #pragma unroll
    for (int j = 0; j < 16; ++j) {
        h1a[j] = 1.f/(1.f + __expf(-h1a[j]));
        h1b[j] = 1.f/(1.f + __expf(-h1b[j]));
    }
    float h2a0 = sw[oB2+0], h2a1 = sw[oB2+1];
    float h2b0 = sw[F2+oB2+0], h2b1 = sw[F2+oB2+1];
    #pragma unroll
    for (int i = 0; i < 16; ++i) {
        h2a0 += h1a[i]*sw[oW2 + i*2 + 0];
        h2a1 += h1a[i]*sw[oW2 + i*2 + 1];
        h2b0 += h1b[i]*sw[F2+oW2 + i*2 + 0];
        h2b1 += h1b[i]*sw[F2+oW2 + i*2 + 1];
    }
    h2a0 = 1.f/(1.f + __expf(-h2a0)); h2a1 = 1.f/(1.f + __expf(-h2a1));
    h2b0 = 1.f/(1.f + __expf(-h2b0)); h2b1 = 1.f/(1.f + __expf(-h2b1));

    const float* pn0 = ne0 + b*TD;
    const float* pn1 = ne1 + b*TD;
    #pragma unroll
    for (int jq = 0; jq < 8; ++jq) {
        float4 ba  = *(const float4*)&sw[oB3 + jq*4];
        float4 wa0 = *(const float4*)&sw[oW3 + jq*4];
        float4 wa1 = *(const float4*)&sw[oW3 + 32 + jq*4];
        float4 bb2 = *(const float4*)&sw[F2+oB3 + jq*4];
        float4 wb0 = *(const float4*)&sw[F2+oW3 + jq*4];
        float4 wb1 = *(const float4*)&sw[F2+oW3 + 32 + jq*4];
        float4 n0 = *(const float4*)&pn0[jq*4];
        float4 n1 = *(const float4*)&pn1[jq*4];
        float4 o1, o2;
        o1.x = tanhf(n0.x*(ba.x + h2a0*wa0.x + h2a1*wa1.x));
        o1.y = tanhf(n0.y*(ba.y + h2a0*wa0.y + h2a1*wa1.y));
        o1.z = tanhf(n0.z*(ba.z + h2a0*wa0.z + h2a1*wa1.z));
        o1.w = tanhf(n0.w*(ba.w + h2a0*wa0.w + h2a1*wa1.w));
        o2.x = tanhf(n1.x*(bb2.x + h2b0*wb0.x + h2b1*wb1.x));
        o2.y = tanhf(n1.y*(bb2.y + h2b0*wb0.y + h2b1*wb1.y));
        o2.z = tanhf(n1.z*(bb2.z + h2b0*wb0.z + h2b1*wb1.z));
        o2.w = tanhf(n1.w*(bb2.w + h2b0*wb0.w + h2b1*wb1.w));
        *(float4*)&nv1[(size_t)p*TD + jq*4] = o1;
        *(float4*)&nv2[(size_t)p*TD + jq*4] = o2;
    }
}

// ---------------------------------------------------------------------------
// K2: per-node weights  W[n][k'][i][o] = sum_d ne2[n,d]*(pool[d,k']+pool[d,k'+2])
// grid: (S/256, N/64), S = 2*CIN*O
// ---------------------------------------------------------------------------
__global__ __launch_bounds__(256) void k_wcomb(
    const float* __restrict__ ne2, const float* __restrict__ pool,
    float* __restrict__ W, int O)
{
    const int S  = 2*CIN*O;
    const int CO = CIN*O;
    int t = threadIdx.x;
    int s = blockIdx.x*256 + t;
    int nbase = blockIdx.y*64;
    __shared__ float sne[64][ED];
    for (int i = t; i < 64*ED; i += 256) {
        int nn = i / ED, d = i - nn*ED;
        sne[nn][d] = ne2[(size_t)(nbase + nn)*ED + d];
    }
    __syncthreads();
    int kp  = s / CO;
    int rem = s - kp*CO;
    float ps[ED];
    #pragma unroll
    for (int d = 0; d < ED; ++d)
        ps[d] = pool[(size_t)(d*4 + kp)*CO + rem] + pool[(size_t)(d*4 + kp + 2)*CO + rem];
    for (int nn = 0; nn < 64; ++nn) {
        float acc = 0.f;
        #pragma unroll
        for (int d = 0; d < ED; ++d) acc += sne[nn][d]*ps[d];
        W[(size_t)(nbase+nn)*S + s] = acc;
    }
}

// ---------------------------------------------------------------------------
// K3: fused A-apply. Y[b,n,:] = (relu(adj)@X + X_row) / (1 + rowsum(relu(adj)))
// adj recomputed from nv1/nv2 per tile (never materialized).
// Block: 64 rows x (all N cols in 64-tiles), 256 threads.
// ---------------------------------------------------------------------------
template<int MODE>
__global__ __launch_bounds__(256) void k_aapply(
    const float* __restrict__ x, const float* __restrict__ state,
    const float* __restrict__ zr,
    const float* __restrict__ nv1g, const float* __restrict__ nv2g,
    float* __restrict__ Y)
{
    __shared__ float s_nv1r[64*32], s_nv2r[64*32];
    __shared__ float s_un[66*68];            // union: {nv1c,nv2c} | X^T tile
    __shared__ float s_a[64*64];
    __shared__ float s_rs[64];
    float* s_nv1c = s_un;
    float* s_nv2c = s_un + 2048;
    float* s_xt   = s_un;

    int t = threadIdx.x;
    int b = blockIdx.y;
    int rbase = blockIdx.x*64;

    {   // stage row nv (xor-swizzled float4 chunks: chunk col = d4 ^ ((r>>2)&7))
        const float4* r1 = (const float4*)(nv1g + ((size_t)b*NN + rbase)*TD);
        const float4* r2 = (const float4*)(nv2g + ((size_t)b*NN + rbase)*TD);
        for (int i = t; i < 512; i += 256) {
            int r = i >> 3, d4 = i & 7;
            int c4 = (d4 ^ ((r >> 2) & 7)) << 2;
            *(float4*)&s_nv1r[r*32 + c4] = r1[i];
            *(float4*)&s_nv2r[r*32 + c4] = r2[i];
        }
    }
    if (t < 64) s_rs[t] = 1.0f;              // +I on the diagonal

    float acc[4][5];
    #pragma unroll
    for (int q = 0; q < 4; ++q)
        #pragma unroll
        for (int j = 0; j < 5; ++j) acc[q][j] = 0.f;

    const int rg = t & 15;                   // row group: rows 4rg..4rg+3
    const int mg = t >> 4;                   // adj col group / mm column-select
    const int r0 = rg << 2;

    for (int mb = 0; mb < NN; mb += 64) {
        const float4* c1g = (const float4*)(nv1g + ((size_t)b*NN + mb)*TD);
        const float4* c2g = (const float4*)(nv2g + ((size_t)b*NN + mb)*TD);
        for (int i = t; i < 512; i += 256) {
            int r = i >> 3, d4 = i & 7;
            int c4 = (d4 ^ ((r >> 2) & 7)) << 2;
            *(float4*)&s_nv1c[r*32 + c4] = c1g[i];
            *(float4*)&s_nv2c[r*32 + c4] = c2g[i];
        }
        __syncthreads();

        {   // adj 4x4 micro-tile: a = relu(nv1r·nv2c - nv2r·nv1c)
            const int m0 = mg << 2;
            float av[4][4];
            #pragma unroll
            for (int ri = 0; ri < 4; ++ri)
                #pragma unroll
                for (int mi = 0; mi < 4; ++mi) av[ri][mi] = 0.f;
            #pragma unroll
            for (int d4 = 0; d4 < 8; ++d4) {
                int cr = (d4 ^ (rg & 7)) << 2;
                int cm = (d4 ^ (mg & 7)) << 2;
                float4 a1[4], a2[4], c1v[4], c2v[4];
                #pragma unroll
                for (int q = 0; q < 4; ++q) {
                    a1[q]  = *(const float4*)&s_nv1r[(r0+q)*32 + cr];
                    a2[q]  = *(const float4*)&s_nv2r[(r0+q)*32 + cr];
                    c1v[q] = *(const float4*)&s_nv1c[(m0+q)*32 + cm];
                    c2v[q] = *(const float4*)&s_nv2c[(m0+q)*32 + cm];
                }
                #pragma unroll
                for (int ri = 0; ri < 4; ++ri)
                    #pragma unroll
                    for (int mi = 0; mi < 4; ++mi) {
                        av[ri][mi] += a1[ri].x*c2v[mi].x - a2[ri].x*c1v[mi].x;
                        av[ri][mi] += a1[ri].y*c2v[mi].y - a2[ri].y*c1v[mi].y;
                        av[ri][mi] += a1[ri].z*c2v[mi].z - a2[ri].z*c1v[mi].z;
                        av[ri][mi] += a1[ri].w*c2v[mi].w - a2[ri].w*c1v[mi].w;
                    }
            }
            int sc = (mg ^ (rg & 7)) << 2;   // xor-swizzled m-chunk position
            #pragma unroll
            for (int ri = 0; ri < 4; ++ri) {
                float4 sv;
                sv.x = fmaxf(av[ri][0], 0.f);
                sv.y = fmaxf(av[ri][1], 0.f);
                sv.z = fmaxf(av[ri][2], 0.f);
                sv.w = fmaxf(av[ri][3], 0.f);
                *(float4*)&s_a[(r0+ri)*64 + sc] = sv;
                atomicAdd(&s_rs[r0+ri], sv.x + sv.y + sv.z + sv.w);
            }
        }
        __syncthreads();

        // stage X^T tile (overwrites the nv_c union region — adj phase done)
        for (int i = t; i < 64*CIN; i += 256) {
            int m = i / CIN;
            int c = i - m*CIN;
            s_xt[c*68 + m] = loadX<MODE>(x, state, zr, b, mb + m, c);
        }
        __syncthreads();

        {   // acc += a_tile @ X_tile (rows 4rg..+3, cols mg+16j)
            #pragma unroll
            for (int m4 = 0; m4 < 16; ++m4) {
                int ac = (m4 ^ (rg & 7)) << 2;
                float4 a0  = *(const float4*)&s_a[(r0+0)*64 + ac];
                float4 a1r = *(const float4*)&s_a[(r0+1)*64 + ac];
                float4 a2r = *(const float4*)&s_a[(r0+2)*64 + ac];
                float4 a3r = *(const float4*)&s_a[(r0+3)*64 + ac];
                #pragma unroll
                for (int j = 0; j < 5; ++j) {
                    int c = mg + (j << 4);
                    if (c < CIN) {
                        float4 xv = *(const float4*)&s_xt[c*68 + (m4 << 2)];
                        acc[0][j] += a0.x*xv.x  + a0.y*xv.y  + a0.z*xv.z  + a0.w*xv.w;
                        acc[1][j] += a1r.x*xv.x + a1r.y*xv.y + a1r.z*xv.z + a1r.w*xv.w;
                        acc[2][j] += a2r.x*xv.x + a2r.y*xv.y + a2r.z*xv.z + a2r.w*xv.w;
                        acc[3][j] += a3r.x*xv.x + a3r.y*xv.y + a3r.z*xv.z + a3r.w*xv.w;
                    }
                }
            }
        }
        __syncthreads();
    }

    #pragma unroll
    for (int q = 0; q < 4; ++q) {
        int r = rbase + r0 + q;
        float rinv = 1.0f / s_rs[r0+q];
        #pragma unroll
        for (int j = 0; j < 5; ++j) {
            int c = mg + (j << 4);
            if (c < CIN) {
                float xr = loadX<MODE>(x, state, zr, b, r, c);
                Y[((size_t)b*NN + r)*CIN + c] = (acc[q][j] + xr)*rinv;
            }
        }
    }
}

// ---------------------------------------------------------------------------
// K4: gate einsum per node: zr = sigmoid(ins@W0 + Ains@W1 + bias)  (O=128)
// block per n; thread owns 4 o's x 4 batches.
// ---------------------------------------------------------------------------
__global__ __launch_bounds__(256) void k_gate(
    const float* __restrict__ x, const float* __restrict__ state,
    const float* __restrict__ Ains, const float* __restrict__ Wg,
    const float* __restrict__ ne2, const float* __restrict__ gate_b,
    float* __restrict__ zr)
{
    int n = blockIdx.x;
    __shared__ float s_inT[CIN*BB], s_aiT[CIN*BB];
    int t = threadIdx.x;
    for (int i = t; i < CIN*BB; i += 256) {
        int c = i >> 5, bb = i & 31;       // BB = 32
        s_inT[c*BB + bb] = loadX<0>(x, state, nullptr, bb, n, c);
        s_aiT[c*BB + bb] = Ains[((size_t)bb*NN + n)*CIN + c];
    }
    __syncthreads();
    int ob = t & 31, bg = t >> 5;          // bg 0..7 -> batches bg*4..+3
    float acc[4][4];
    #pragma unroll
    for (int k = 0; k < 4; ++k)
        #pragma unroll
        for (int j = 0; j < 4; ++j) acc[k][j] = 0.f;
    const float* W0 = Wg + (size_t)n*(2*CIN*OG);
    const float* W1 = W0 + CIN*OG;
    for (int i = 0; i < CIN; ++i) {
        float4 iv = *(const float4*)&s_inT[i*BB + bg*4];
        float4 av = *(const float4*)&s_aiT[i*BB + bg*4];
        #pragma unroll
        for (int k = 0; k < 4; ++k) {
            float w0 = W0[i*OG + ob + (k<<5)];
            float w1 = W1[i*OG + ob + (k<<5)];
            acc[k][0] += iv.x*w0 + av.x*w1;
            acc[k][1] += iv.y*w0 + av.y*w1;
            acc[k][2] += iv.z*w0 + av.z*w1;
            acc[k][3] += iv.w*w0 + av.w*w1;
        }
    }
    #pragma unroll
    for (int k = 0; k < 4; ++k) {
        int o = ob + (k<<5);
        float bias = 0.f;
        #pragma unroll
        for (int d = 0; d < ED; ++d) bias += ne2[(size_t)n*ED + d]*gate_b[d*OG + o];
        #pragma unroll
        for (int j = 0; j < 4; ++j) {
            float v = 1.f/(1.f + __expf(-(acc[k][j] + bias)));
            zr[((size_t)(bg*4 + j)*NN + n)*OG + o] = v;
        }
    }
}

// ---------------------------------------------------------------------------
// K5: upd einsum + final combine: out = r*state + (1-r)*tanh(cand@W0 + Acand@W1 + bias)
// ---------------------------------------------------------------------------
__global__ __launch_bounds__(256) void k_upd(
    const float* __restrict__ x, const float* __restrict__ state,
    const float* __restrict__ zr, const float* __restrict__ Acand,
    const float* __restrict__ Wu, const float* __restrict__ ne2,
    const float* __restrict__ upd_b, float* __restrict__ out)
{
    int n = blockIdx.x;
    __shared__ float s_cT[CIN*BB], s_aT[CIN*BB];
    int t = threadIdx.x;
    for (int i = t; i < CIN*BB; i += 256) {
        int c = i >> 5, bb = i & 31;
        s_cT[c*BB + bb] = loadX<1>(x, state, zr, bb, n, c);
        s_aT[c*BB + bb] = Acand[((size_t)bb*NN + n)*CIN + c];
    }
    __syncthreads();
    int ob = t & 15, bg = t >> 4;          // bg 0..15 -> batches bg*2, bg*2+1
    float acc[4][2];
    #pragma unroll
    for (int k = 0; k < 4; ++k) { acc[k][0] = 0.f; acc[k][1] = 0.f; }
    const float* W0 = Wu + (size_t)n*(2*CIN*OU);
    const float* W1 = W0 + CIN*OU;
    for (int i = 0; i < CIN; ++i) {
        float2 iv = *(const float2*)&s_cT[i*BB + bg*2];
        float2 av = *(const float2*)&s_aT[i*BB + bg*2];
        #pragma unroll
        for (int k = 0; k < 4; ++k) {
            float w0 = W0[i*OU + ob + (k<<4)];
            float w1 = W1[i*OU + ob + (k<<4)];
            acc[k][0] += iv.x*w0 + av.x*w1;
            acc[k][1] += iv.y*w0 + av.y*w1;
        }
    }
    #pragma unroll
    for (int k = 0; k < 4; ++k) {
        int o = ob + (k<<4);
        float bias = 0.f;
        #pragma unroll
        for (int d = 0; d < ED; ++d) bias += ne2[(size_t)n*ED + d]*upd_b[d*OU + o];
        #pragma unroll
        for (int j = 0; j < 2; ++j) {
            int bb = bg*2 + j;
            float hc = tanhf(acc[k][j] + bias);
            size_t base = (size_t)bb*NN + n;
            float st = state[base*DOUT + o];
            float r  = zr[base*OG + DOUT + o];
            out[base*DOUT + o] = r*st + (1.f - r)*hc;
        }
    }
}

// ---------------------------------------------------------------------------
extern "C" void kernel_launch(void* const* d_in, const int* in_sizes, int n_in,
                              void* d_out, int out_size, void* d_ws, size_t ws_size,
                              hipStream_t stream)
{
    const float* x      = (const float*)d_in[0];
    const float* state  = (const float*)d_in[1];
    const float* ne0    = (const float*)d_in[2];
    const float* ne1    = (const float*)d_in[3];
    const float* ne2    = (const float*)d_in[4];
    const float* f1w1   = (const float*)d_in[5];
    const float* f1b1   = (const float*)d_in[6];
    const float* f1w2   = (const float*)d_in[7];
    const float* f1b2   = (const float*)d_in[8];
    const float* f1w3   = (const float*)d_in[9];
    const float* f1b3   = (const float*)d_in[10];
    const float* f2w1   = (const float*)d_in[11];
    const float* f2b1   = (const float*)d_in[12];
    const float* f2w2   = (const float*)d_in[13];
    const float* f2b2   = (const float*)d_in[14];
    const float* f2w3   = (const float*)d_in[15];
    const float* f2b3   = (const float*)d_in[16];
    const float* gate_w = (const float*)d_in[17];
    const float* gate_b = (const float*)d_in[18];
    const float* upd_w  = (const float*)d_in[19];
    const float* upd_b  = (const float*)d_in[20];

    // workspace layout (floats), with aliasing:
    //  AX: Ains then Acand;  W: gate weights then upd weights.  total ~103 MB
    float* ws  = (float*)d_ws;
    float* nv1 = ws;
    float* nv2 = nv1 + (size_t)BB*NN*TD;
    float* AX  = nv2 + (size_t)BB*NN*TD;
    float* zr  = AX  + (size_t)BB*NN*CIN;
    float* W   = zr  + (size_t)BB*NN*OG;
    float* out = (float*)d_out;

    k_nv<<<dim3(BB*NN/256), 256, 0, stream>>>(x, state, ne0, ne1,
        f1w1, f1b1, f1w2, f1b2, f1w3, f1b3,
        f2w1, f2b1, f2w2, f2b2, f2w3, f2b3, nv1, nv2);

    k_wcomb<<<dim3(2*CIN*OG/256, NN/64), 256, 0, stream>>>(ne2, gate_w, W, OG);

    k_aapply<0><<<dim3(NN/64, BB), 256, 0, stream>>>(x, state, zr, nv1, nv2, AX);

    k_gate<<<dim3(NN), 256, 0, stream>>>(x, state, AX, W, ne2, gate_b, zr);

    k_wcomb<<<dim3(2*CIN*OU/256, NN/64), 256, 0, stream>>>(ne2, upd_w, W, OU);

    k_aapply<1><<<dim3(NN/64, BB), 256, 0, stream>>>(x, state, zr, nv1, nv2, AX);

    k_upd<<<dim3(NN), 256, 0, stream>>>(x, state, zr, AX, W, ne2, upd_b, out);
}

// Round 2
// 319.532 us; speedup vs baseline: 4.4704x; 4.4704x over previous
//
#include <hip/hip_runtime.h>
#include <math.h>

#define BB   32      // batch
#define NN   1024    // nodes
#define DIN  2
#define DOUT 64
#define CIN  66      // DIN + DOUT
#define TD   32
#define ED   10
#define OG   128     // 2*DOUT (gate out)
#define OU   64      // upd out

typedef __bf16 bf16x8 __attribute__((ext_vector_type(8)));
typedef float  f32x4  __attribute__((ext_vector_type(4)));
typedef short  s16x8  __attribute__((ext_vector_type(8)));

__device__ __forceinline__ unsigned short f2b(float f) {
    __bf16 h = (__bf16)f;
    return *(unsigned short*)&h;
}

// ---------------------------------------------------------------------------
// helper: X[b,m,c] on the fly (fp32). MODE 0: ins = concat(x,state).
// MODE 1: cand = concat(x, z*state), z = zr[...,:64].
// ---------------------------------------------------------------------------
template<int MODE>
__device__ __forceinline__ float loadX(const float* __restrict__ x,
                                       const float* __restrict__ state,
                                       const float* __restrict__ zr,
                                       int b, int m, int c)
{
    if (c < DIN) return x[((size_t)b*NN + m)*DIN + c];
    int j = c - DIN;
    float s = state[((size_t)b*NN + m)*DOUT + j];
    if (MODE == 1) s *= zr[((size_t)b*NN + m)*OG + j];
    return s;
}

// ---------------------------------------------------------------------------
// K1: tiny MLPs -> nv1, nv2 (bf16 out). One thread per (b,n).
// ---------------------------------------------------------------------------
__global__ __launch_bounds__(256) void k_nv(
    const float* __restrict__ x, const float* __restrict__ state,
    const float* __restrict__ ne0, const float* __restrict__ ne1,
    const float* __restrict__ w11, const float* __restrict__ b11,
    const float* __restrict__ w12, const float* __restrict__ b12,
    const float* __restrict__ w13, const float* __restrict__ b13,
    const float* __restrict__ w21, const float* __restrict__ b21,
    const float* __restrict__ w22, const float* __restrict__ b22,
    const float* __restrict__ w23, const float* __restrict__ b23,
    unsigned short* __restrict__ nv1b, unsigned short* __restrict__ nv2b)
{
    const int oW1 = 0, oB1 = 1056, oW2 = 1072, oB2 = 1104, oW3 = 1108, oB3 = 1172, F2 = 1204;
    __shared__ float sw[2408];
    int t = threadIdx.x;
    for (int i = t; i < 1056; i += 256) { sw[oW1+i] = w11[i]; sw[F2+oW1+i] = w21[i]; }
    if (t < 16) { sw[oB1+t] = b11[t]; sw[F2+oB1+t] = b21[t]; }
    if (t < 32) { sw[oW2+t] = w12[t]; sw[F2+oW2+t] = w22[t]; }
    if (t < 2)  { sw[oB2+t] = b12[t]; sw[F2+oB2+t] = b22[t]; }
    if (t < 64) { sw[oW3+t] = w13[t]; sw[F2+oW3+t] = w23[t]; }
    if (t >= 64 && t < 96) { sw[oB3+t-64] = b13[t-64]; sw[F2+oB3+t-64] = b23[t-64]; }
    __syncthreads();

    int p = blockIdx.x*256 + t;
    int b = p >> 10;

    float h1a[16], h1b[16];
    #pragma unroll
    for (int j = 0; j < 16; ++j) { h1a[j] = sw[oB1+j]; h1b[j] = sw[F2+oB1+j]; }
    for (int i = 0; i < CIN; ++i) {
        float v = (i < DIN) ? x[(size_t)p*DIN + i] : state[(size_t)p*DOUT + (i-DIN)];
        #pragma unroll
        for (int jq = 0; jq < 4; ++jq) {
            float4 wa = *(const float4*)&sw[oW1 + i*16 + jq*4];
            float4 wb = *(const float4*)&sw[F2 + oW1 + i*16 + jq*4];
            h1a[jq*4+0] += v*wa.x; h1a[jq*4+1] += v*wa.y;
            h1a[jq*4+2] += v*wa.z; h1a[jq*4+3] += v*wa.w;
            h1b[jq*4+0] += v*wb.x; h1b[jq*4+1] += v*wb.y;
            h1b[jq*4+2] += v*wb.z; h1b[jq*4+3] += v*wb.w;
        }
    }
    #pragma unroll
    for (int j = 0; j < 16; ++j) {
        h1a[j] = 1.f/(1.f + __expf(-h1a[j]));
        h1b[j] = 1.f/(1.f + __expf(-h1b[j]));
    }
    float h2a0 = sw[oB2+0], h2a1 = sw[oB2+1];
    float h2b0 = sw[F2+oB2+0], h2b1 = sw[F2+oB2+1];
    #pragma unroll
    for (int i = 0; i < 16; ++i) {
        h2a0 += h1a[i]*sw[oW2 + i*2 + 0];
        h2a1 += h1a[i]*sw[oW2 + i*2 + 1];
        h2b0 += h1b[i]*sw[F2+oW2 + i*2 + 0];
        h2b1 += h1b[i]*sw[F2+oW2 + i*2 + 1];
    }
    h2a0 = 1.f/(1.f + __expf(-h2a0)); h2a1 = 1.f/(1.f + __expf(-h2a1));
    h2b0 = 1.f/(1.f + __expf(-h2b0)); h2b1 = 1.f/(1.f + __expf(-h2b1));

    const float* pn0 = ne0 + b*TD;
    const float* pn1 = ne1 + b*TD;
    #pragma unroll
    for (int jq = 0; jq < 8; ++jq) {
        float4 ba  = *(const float4*)&sw[oB3 + jq*4];
        float4 wa0 = *(const float4*)&sw[oW3 + jq*4];
        float4 wa1 = *(const float4*)&sw[oW3 + 32 + jq*4];
        float4 bb2 = *(const float4*)&sw[F2+oB3 + jq*4];
        float4 wb0 = *(const float4*)&sw[F2+oW3 + jq*4];
        float4 wb1 = *(const float4*)&sw[F2+oW3 + 32 + jq*4];
        float4 n0 = *(const float4*)&pn0[jq*4];
        float4 n1 = *(const float4*)&pn1[jq*4];
        ushort4 u1, u2;
        u1.x = f2b(tanhf(n0.x*(ba.x + h2a0*wa0.x + h2a1*wa1.x)));
        u1.y = f2b(tanhf(n0.y*(ba.y + h2a0*wa0.y + h2a1*wa1.y)));
        u1.z = f2b(tanhf(n0.z*(ba.z + h2a0*wa0.z + h2a1*wa1.z)));
        u1.w = f2b(tanhf(n0.w*(ba.w + h2a0*wa0.w + h2a1*wa1.w)));
        u2.x = f2b(tanhf(n1.x*(bb2.x + h2b0*wb0.x + h2b1*wb1.x)));
        u2.y = f2b(tanhf(n1.y*(bb2.y + h2b0*wb0.y + h2b1*wb1.y)));
        u2.z = f2b(tanhf(n1.z*(bb2.z + h2b0*wb0.z + h2b1*wb1.z)));
        u2.w = f2b(tanhf(n1.w*(bb2.w + h2b0*wb0.w + h2b1*wb1.w)));
        *(ushort4*)&nv1b[(size_t)p*TD + jq*4] = u1;
        *(ushort4*)&nv2b[(size_t)p*TD + jq*4] = u2;
    }
}

// ---------------------------------------------------------------------------
// K2: per-node weights  W[n][k'][i][o] = sum_d ne2[n,d]*(pool[d,k']+pool[d,k'+2])
// ---------------------------------------------------------------------------
__global__ __launch_bounds__(256) void k_wcomb(
    const float* __restrict__ ne2, const float* __restrict__ pool,
    float* __restrict__ W, int O)
{
    const int S  = 2*CIN*O;
    const int CO = CIN*O;
    int t = threadIdx.x;
    int s = blockIdx.x*256 + t;
    int nbase = blockIdx.y*64;
    __shared__ float sne[64][ED];
    for (int i = t; i < 64*ED; i += 256) {
        int nn = i / ED, d = i - nn*ED;
        sne[nn][d] = ne2[(size_t)(nbase + nn)*ED + d];
    }
    __syncthreads();
    int kp  = s / CO;
    int rem = s - kp*CO;
    float ps[ED];
    #pragma unroll
    for (int d = 0; d < ED; ++d)
        ps[d] = pool[(size_t)(d*4 + kp)*CO + rem] + pool[(size_t)(d*4 + kp + 2)*CO + rem];
    for (int nn = 0; nn < 64; ++nn) {
        float acc = 0.f;
        #pragma unroll
        for (int d = 0; d < ED; ++d) acc += sne[nn][d]*ps[d];
        W[(size_t)(nbase+nn)*S + s] = acc;
    }
}

// ---------------------------------------------------------------------------
// K_XT: build XTg[b][68][1024] bf16: rows 0-1 = x cols, 2-65 = state (MODE1:
// z*state), 66 = ones (rowsum trick), 67 = zeros. Transposed for MFMA B-frags.
// ---------------------------------------------------------------------------
template<int MODE>
__global__ __launch_bounds__(256) void k_xt(
    const float* __restrict__ x, const float* __restrict__ state,
    const float* __restrict__ zr, unsigned short* __restrict__ XTg)
{
    __shared__ unsigned short st[68*72];   // [c][m], m-stride 72 (16B aligned rows)
    int t = threadIdx.x;
    int b = blockIdx.y, m0 = blockIdx.x*64;
    for (int i = t; i < 1024; i += 256) {       // 64 m x 16 col-quads (state)
        int m = i >> 4, cq = i & 15;
        size_t base = (size_t)b*NN + m0 + m;
        float4 v = *(const float4*)&state[base*DOUT + cq*4];
        if (MODE == 1) {
            float4 z = *(const float4*)&zr[base*OG + cq*4];
            v.x *= z.x; v.y *= z.y; v.z *= z.z; v.w *= z.w;
        }
        st[(2 + cq*4 + 0)*72 + m] = f2b(v.x);
        st[(2 + cq*4 + 1)*72 + m] = f2b(v.y);
        st[(2 + cq*4 + 2)*72 + m] = f2b(v.z);
        st[(2 + cq*4 + 3)*72 + m] = f2b(v.w);
    }
    if (t < 128) {                               // x cols 0,1
        int m = t >> 1, c = t & 1;
        st[c*72 + m] = f2b(x[((size_t)b*NN + m0 + m)*DIN + c]);
    }
    __syncthreads();
    const unsigned int ONE2 = 0x3F803F80u;       // two bf16 1.0
    for (int i = t; i < 68*8; i += 256) {
        int c = i >> 3, ch = i & 7;
        uint4 v;
        if (c < 66)      v = *(const uint4*)&st[c*72 + ch*8];
        else if (c == 66) v = make_uint4(ONE2, ONE2, ONE2, ONE2);
        else              v = make_uint4(0, 0, 0, 0);
        *(uint4*)&XTg[((size_t)b*68 + c)*1024 + m0 + ch*8] = v;
    }
}

// ---------------------------------------------------------------------------
// K3: fused A-apply via MFMA. Per block: 64 rows of one batch.
//   S = nv1r.nv2c^T - nv2r.nv1c^T  (mfma 16x16x32 bf16, K=32 in one inst)
//   P = relu(S) -> bf16 -> LDS (A-layout);  acc += P @ XT-tile (5 col-tiles of
//   16: cols 0-65 = ins/cand, col 66 = ones => rowsum).  Y = (acc+X)/(1+rs).
// LDS strides: nv 40, P/XT 72 -> 16B-aligned ds_read_b128, ~2-way banks.
// ---------------------------------------------------------------------------
template<int MODE>
__global__ __launch_bounds__(256) void k_aapply(
    const unsigned short* __restrict__ nv1b, const unsigned short* __restrict__ nv2b,
    const unsigned short* __restrict__ XTg,
    const float* __restrict__ x, const float* __restrict__ state,
    const float* __restrict__ zr, float* __restrict__ Y)
{
    __shared__ unsigned short s_nv1r[64*40], s_nv2r[64*40];
    __shared__ unsigned short s_nv1c[64*40], s_nv2c[64*40];
    __shared__ unsigned short s_p[64*72];
    __shared__ unsigned short s_xt[80*72];
    __shared__ float s_rs[64];

    int t = threadIdx.x;
    int b = blockIdx.y, rbase = blockIdx.x*64;
    int w = t >> 6, lane = t & 63, lq = lane >> 4, ln = lane & 15;

    // stage row nv once (16B chunks, 16B-aligned both sides)
    for (int i = t; i < 512; i += 256) {
        int arr = i >> 8, j = i & 255;
        int node = j >> 2, ch = j & 3;
        const unsigned short* src = (arr ? nv2b : nv1b)
            + ((size_t)b*NN + rbase + node)*TD + ch*8;
        unsigned short* dst = (arr ? s_nv2r : s_nv1r) + node*40 + ch*8;
        *(uint4*)dst = *(const uint4*)src;
    }
    for (int i = t; i < 12*72; i += 256) s_xt[68*72 + i] = 0;   // pad cols 67..79 zero
    __syncthreads();

    // constant A-fragments: A[m=ln][k=lq*8+j]; a2n = -nv2r (sign-bit flip, exact)
    bf16x8 a1 = *(const bf16x8*)&s_nv1r[(16*w + ln)*40 + lq*8];
    s16x8 a2s = *(const s16x8*)&s_nv2r[(16*w + ln)*40 + lq*8];
    const s16x8 sgn = {(short)0x8000,(short)0x8000,(short)0x8000,(short)0x8000,
                       (short)0x8000,(short)0x8000,(short)0x8000,(short)0x8000};
    a2s ^= sgn;
    bf16x8 a2n = (bf16x8)a2s;

    f32x4 acc[5];
    #pragma unroll
    for (int i = 0; i < 5; ++i) acc[i] = (f32x4){0.f,0.f,0.f,0.f};
    const f32x4 zero4 = {0.f,0.f,0.f,0.f};

    for (int mb = 0; mb < NN; mb += 64) {
        __syncthreads();                          // prior tile's reads done
        for (int i = t; i < 512; i += 256) {      // stage col nv
            int arr = i >> 8, j = i & 255;
            int node = j >> 2, ch = j & 3;
            const unsigned short* src = (arr ? nv2b : nv1b)
                + ((size_t)b*NN + mb + node)*TD + ch*8;
            unsigned short* dst = (arr ? s_nv2c : s_nv1c) + node*40 + ch*8;
            *(uint4*)dst = *(const uint4*)src;
        }
        for (int i = t; i < 544; i += 256) {      // stage XT tile (68 rows x 64 m)
            int c = i >> 3, ch = i & 7;
            *(uint4*)&s_xt[c*72 + ch*8] =
                *(const uint4*)&XTg[((size_t)b*68 + c)*1024 + mb + ch*8];
        }
        __syncthreads();

        // ---- S phase: wave w owns rows 16w..16w+15, computes all 64 cols
        #pragma unroll
        for (int j0t = 0; j0t < 4; ++j0t) {
            int j0 = j0t*16;
            bf16x8 b2 = *(const bf16x8*)&s_nv2c[(j0 + ln)*40 + lq*8];
            bf16x8 b1 = *(const bf16x8*)&s_nv1c[(j0 + ln)*40 + lq*8];
            f32x4 s = __builtin_amdgcn_mfma_f32_16x16x32_bf16(a1,  b2, zero4, 0, 0, 0);
            s       = __builtin_amdgcn_mfma_f32_16x16x32_bf16(a2n, b1, s,     0, 0, 0);
            // C layout: col = ln, row = lq*4 + r  -> write P bf16 (own rows only)
            #pragma unroll
            for (int r = 0; r < 4; ++r) {
                float p = fmaxf(s[r], 0.f);
                *(__bf16*)&s_p[(16*w + lq*4 + r)*72 + j0 + ln] = (__bf16)p;
            }
        }

        // ---- PV phase: acc += P(16x64) @ XT(64x80); same-wave P, lgkm-ordered
        bf16x8 pa0 = *(const bf16x8*)&s_p[(16*w + ln)*72 +      lq*8];
        bf16x8 pa1 = *(const bf16x8*)&s_p[(16*w + ln)*72 + 32 + lq*8];
        #pragma unroll
        for (int n0t = 0; n0t < 5; ++n0t) {
            int n0 = n0t*16;
            bf16x8 xb0 = *(const bf16x8*)&s_xt[(n0 + ln)*72 +      lq*8];
            bf16x8 xb1 = *(const bf16x8*)&s_xt[(n0 + ln)*72 + 32 + lq*8];
            acc[n0t] = __builtin_amdgcn_mfma_f32_16x16x32_bf16(pa0, xb0, acc[n0t], 0, 0, 0);
            acc[n0t] = __builtin_amdgcn_mfma_f32_16x16x32_bf16(pa1, xb1, acc[n0t], 0, 0, 0);
        }
    }

    // rowsum lives at output col 66 = tile 4, ln==2; broadcast via LDS (same wave)
    if (ln == 2) {
        #pragma unroll
        for (int r = 0; r < 4; ++r) s_rs[16*w + lq*4 + r] = acc[4][r];
    }
    float rinv[4];
    #pragma unroll
    for (int r = 0; r < 4; ++r) rinv[r] = 1.0f / (1.0f + s_rs[16*w + lq*4 + r]);

    #pragma unroll
    for (int n0t = 0; n0t < 5; ++n0t) {
        int c = n0t*16 + ln;
        if (c < CIN) {
            #pragma unroll
            for (int r = 0; r < 4; ++r) {
                int gr = rbase + 16*w + lq*4 + r;
                float xr = loadX<MODE>(x, state, zr, b, gr, c);
                Y[((size_t)b*NN + gr)*CIN + c] = (acc[n0t][r] + xr) * rinv[r];
            }
        }
    }
}

// ---------------------------------------------------------------------------
// K4: gate einsum per node: zr = sigmoid(ins@W0 + Ains@W1 + bias)  (O=128)
// ---------------------------------------------------------------------------
__global__ __launch_bounds__(256) void k_gate(
    const float* __restrict__ x, const float* __restrict__ state,
    const float* __restrict__ Ains, const float* __restrict__ Wg,
    const float* __restrict__ ne2, const float* __restrict__ gate_b,
    float* __restrict__ zr)
{
    int n = blockIdx.x;
    __shared__ float s_inT[CIN*BB], s_aiT[CIN*BB];
    int t = threadIdx.x;
    for (int i = t; i < CIN*BB; i += 256) {
        int c = i >> 5, bb = i & 31;
        s_inT[c*BB + bb] = loadX<0>(x, state, nullptr, bb, n, c);
        s_aiT[c*BB + bb] = Ains[((size_t)bb*NN + n)*CIN + c];
    }
    __syncthreads();
    int ob = t & 31, bg = t >> 5;
    float acc[4][4];
    #pragma unroll
    for (int k = 0; k < 4; ++k)
        #pragma unroll
        for (int j = 0; j < 4; ++j) acc[k][j] = 0.f;
    const float* W0 = Wg + (size_t)n*(2*CIN*OG);
    const float* W1 = W0 + CIN*OG;
    for (int i = 0; i < CIN; ++i) {
        float4 iv = *(const float4*)&s_inT[i*BB + bg*4];
        float4 av = *(const float4*)&s_aiT[i*BB + bg*4];
        #pragma unroll
        for (int k = 0; k < 4; ++k) {
            float w0 = W0[i*OG + ob + (k<<5)];
            float w1 = W1[i*OG + ob + (k<<5)];
            acc[k][0] += iv.x*w0 + av.x*w1;
            acc[k][1] += iv.y*w0 + av.y*w1;
            acc[k][2] += iv.z*w0 + av.z*w1;
            acc[k][3] += iv.w*w0 + av.w*w1;
        }
    }
    #pragma unroll
    for (int k = 0; k < 4; ++k) {
        int o = ob + (k<<5);
        float bias = 0.f;
        #pragma unroll
        for (int d = 0; d < ED; ++d) bias += ne2[(size_t)n*ED + d]*gate_b[d*OG + o];
        #pragma unroll
        for (int j = 0; j < 4; ++j) {
            float v = 1.f/(1.f + __expf(-(acc[k][j] + bias)));
            zr[((size_t)(bg*4 + j)*NN + n)*OG + o] = v;
        }
    }
}

// ---------------------------------------------------------------------------
// K5: upd einsum + final: out = r*state + (1-r)*tanh(cand@W0 + Acand@W1 + bias)
// ---------------------------------------------------------------------------
__global__ __launch_bounds__(256) void k_upd(
    const float* __restrict__ x, const float* __restrict__ state,
    const float* __restrict__ zr, const float* __restrict__ Acand,
    const float* __restrict__ Wu, const float* __restrict__ ne2,
    const float* __restrict__ upd_b, float* __restrict__ out)
{
    int n = blockIdx.x;
    __shared__ float s_cT[CIN*BB], s_aT[CIN*BB];
    int t = threadIdx.x;
    for (int i = t; i < CIN*BB; i += 256) {
        int c = i >> 5, bb = i & 31;
        s_cT[c*BB + bb] = loadX<1>(x, state, zr, bb, n, c);
        s_aT[c*BB + bb] = Acand[((size_t)bb*NN + n)*CIN + c];
    }
    __syncthreads();
    int ob = t & 15, bg = t >> 4;
    float acc[4][2];
    #pragma unroll
    for (int k = 0; k < 4; ++k) { acc[k][0] = 0.f; acc[k][1] = 0.f; }
    const float* W0 = Wu + (size_t)n*(2*CIN*OU);
    const float* W1 = W0 + CIN*OU;
    for (int i = 0; i < CIN; ++i) {
        float2 iv = *(const float2*)&s_cT[i*BB + bg*2];
        float2 av = *(const float2*)&s_aT[i*BB + bg*2];
        #pragma unroll
        for (int k = 0; k < 4; ++k) {
            float w0 = W0[i*OU + ob + (k<<4)];
            float w1 = W1[i*OU + ob + (k<<4)];
            acc[k][0] += iv.x*w0 + av.x*w1;
            acc[k][1] += iv.y*w0 + av.y*w1;
        }
    }
    #pragma unroll
    for (int k = 0; k < 4; ++k) {
        int o = ob + (k<<4);
        float bias = 0.f;
        #pragma unroll
        for (int d = 0; d < ED; ++d) bias += ne2[(size_t)n*ED + d]*upd_b[d*OU + o];
        #pragma unroll
        for (int j = 0; j < 2; ++j) {
            int bb = bg*2 + j;
            float hc = tanhf(acc[k][j] + bias);
            size_t base = (size_t)bb*NN + n;
            float st = state[base*DOUT + o];
            float r  = zr[base*OG + DOUT + o];
            out[base*DOUT + o] = r*st + (1.f - r)*hc;
        }
    }
}

// ---------------------------------------------------------------------------
extern "C" void kernel_launch(void* const* d_in, const int* in_sizes, int n_in,
                              void* d_out, int out_size, void* d_ws, size_t ws_size,
                              hipStream_t stream)
{
    const float* x      = (const float*)d_in[0];
    const float* state  = (const float*)d_in[1];
    const float* ne0    = (const float*)d_in[2];
    const float* ne1    = (const float*)d_in[3];
    const float* ne2    = (const float*)d_in[4];
    const float* f1w1   = (const float*)d_in[5];
    const float* f1b1   = (const float*)d_in[6];
    const float* f1w2   = (const float*)d_in[7];
    const float* f1b2   = (const float*)d_in[8];
    const float* f1w3   = (const float*)d_in[9];
    const float* f1b3   = (const float*)d_in[10];
    const float* f2w1   = (const float*)d_in[11];
    const float* f2b1   = (const float*)d_in[12];
    const float* f2w2   = (const float*)d_in[13];
    const float* f2b2   = (const float*)d_in[14];
    const float* f2w3   = (const float*)d_in[15];
    const float* f2b3   = (const float*)d_in[16];
    const float* gate_w = (const float*)d_in[17];
    const float* gate_b = (const float*)d_in[18];
    const float* upd_w  = (const float*)d_in[19];
    const float* upd_b  = (const float*)d_in[20];

    // ws layout (bytes, all 16B-aligned): nv1b 2M | nv2b 2M | XTg 4.25M |
    // AX 8.25M | zr 16M | W 69.2M  => ~101.7 MB
    unsigned short* nv1b = (unsigned short*)d_ws;
    unsigned short* nv2b = nv1b + (size_t)BB*NN*TD;
    unsigned short* XTg  = nv2b + (size_t)BB*NN*TD;
    float* AX = (float*)(XTg + (size_t)BB*68*NN);
    float* zr = AX + (size_t)BB*NN*CIN;
    float* W  = zr + (size_t)BB*NN*OG;
    float* out = (float*)d_out;

    k_nv<<<dim3(BB*NN/256), 256, 0, stream>>>(x, state, ne0, ne1,
        f1w1, f1b1, f1w2, f1b2, f1w3, f1b3,
        f2w1, f2b1, f2w2, f2b2, f2w3, f2b3, nv1b, nv2b);

    k_wcomb<<<dim3(2*CIN*OG/256, NN/64), 256, 0, stream>>>(ne2, gate_w, W, OG);

    k_xt<0><<<dim3(NN/64, BB), 256, 0, stream>>>(x, state, nullptr, XTg);

    k_aapply<0><<<dim3(NN/64, BB), 256, 0, stream>>>(nv1b, nv2b, XTg,
                                                     x, state, nullptr, AX);

    k_gate<<<dim3(NN), 256, 0, stream>>>(x, state, AX, W, ne2, gate_b, zr);

    k_xt<1><<<dim3(NN/64, BB), 256, 0, stream>>>(x, state, zr, XTg);

    k_wcomb<<<dim3(2*CIN*OU/256, NN/64), 256, 0, stream>>>(ne2, upd_w, W, OU);

    k_aapply<1><<<dim3(NN/64, BB), 256, 0, stream>>>(nv1b, nv2b, XTg,
                                                     x, state, zr, AX);

    k_upd<<<dim3(NN), 256, 0, stream>>>(x, state, zr, AX, W, ne2, upd_b, out);
}

// Round 3
// 317.036 us; speedup vs baseline: 4.5055x; 1.0079x over previous
//
#include <hip/hip_runtime.h>
#include <math.h>

#define BB   32      // batch
#define NN   1024    // nodes
#define DIN  2
#define DOUT 64
#define CIN  66      // DIN + DOUT
#define TD   32
#define ED   10
#define OG   128     // 2*DOUT (gate out)
#define OU   64      // upd out
#define KP   160     // padded K for the einsum GEMM (132 real)

typedef __bf16 bf16x8 __attribute__((ext_vector_type(8)));
typedef float  f32x4  __attribute__((ext_vector_type(4)));
typedef short  s16x8  __attribute__((ext_vector_type(8)));

__device__ __forceinline__ unsigned short f2b(float f) {
    __bf16 h = (__bf16)f;
    return *(unsigned short*)&h;
}

// ---------------------------------------------------------------------------
// helper: X[b,m,c] on the fly (fp32). MODE 0: ins = concat(x,state).
// MODE 1: cand = concat(x, z*state), z = zr[...,:64].
// ---------------------------------------------------------------------------
template<int MODE>
__device__ __forceinline__ float loadX(const float* __restrict__ x,
                                       const float* __restrict__ state,
                                       const float* __restrict__ zr,
                                       int b, int m, int c)
{
    if (c < DIN) return x[((size_t)b*NN + m)*DIN + c];
    int j = c - DIN;
    float s = state[((size_t)b*NN + m)*DOUT + j];
    if (MODE == 1) s *= zr[((size_t)b*NN + m)*OG + j];
    return s;
}

// ---------------------------------------------------------------------------
// K1: tiny MLPs -> nv1, nv2 (bf16 out). One thread per (b,n).
// ---------------------------------------------------------------------------
__global__ __launch_bounds__(256) void k_nv(
    const float* __restrict__ x, const float* __restrict__ state,
    const float* __restrict__ ne0, const float* __restrict__ ne1,
    const float* __restrict__ w11, const float* __restrict__ b11,
    const float* __restrict__ w12, const float* __restrict__ b12,
    const float* __restrict__ w13, const float* __restrict__ b13,
    const float* __restrict__ w21, const float* __restrict__ b21,
    const float* __restrict__ w22, const float* __restrict__ b22,
    const float* __restrict__ w23, const float* __restrict__ b23,
    unsigned short* __restrict__ nv1b, unsigned short* __restrict__ nv2b)
{
    const int oW1 = 0, oB1 = 1056, oW2 = 1072, oB2 = 1104, oW3 = 1108, oB3 = 1172, F2 = 1204;
    __shared__ float sw[2408];
    int t = threadIdx.x;
    for (int i = t; i < 1056; i += 256) { sw[oW1+i] = w11[i]; sw[F2+oW1+i] = w21[i]; }
    if (t < 16) { sw[oB1+t] = b11[t]; sw[F2+oB1+t] = b21[t]; }
    if (t < 32) { sw[oW2+t] = w12[t]; sw[F2+oW2+t] = w22[t]; }
    if (t < 2)  { sw[oB2+t] = b12[t]; sw[F2+oB2+t] = b22[t]; }
    if (t < 64) { sw[oW3+t] = w13[t]; sw[F2+oW3+t] = w23[t]; }
    if (t >= 64 && t < 96) { sw[oB3+t-64] = b13[t-64]; sw[F2+oB3+t-64] = b23[t-64]; }
    __syncthreads();

    int p = blockIdx.x*256 + t;
    int b = p >> 10;

    float h1a[16], h1b[16];
    #pragma unroll
    for (int j = 0; j < 16; ++j) { h1a[j] = sw[oB1+j]; h1b[j] = sw[F2+oB1+j]; }
    for (int i = 0; i < CIN; ++i) {
        float v = (i < DIN) ? x[(size_t)p*DIN + i] : state[(size_t)p*DOUT + (i-DIN)];
        #pragma unroll
        for (int jq = 0; jq < 4; ++jq) {
            float4 wa = *(const float4*)&sw[oW1 + i*16 + jq*4];
            float4 wb = *(const float4*)&sw[F2 + oW1 + i*16 + jq*4];
            h1a[jq*4+0] += v*wa.x; h1a[jq*4+1] += v*wa.y;
            h1a[jq*4+2] += v*wa.z; h1a[jq*4+3] += v*wa.w;
            h1b[jq*4+0] += v*wb.x; h1b[jq*4+1] += v*wb.y;
            h1b[jq*4+2] += v*wb.z; h1b[jq*4+3] += v*wb.w;
        }
    }
    #pragma unroll
    for (int j = 0; j < 16; ++j) {
        h1a[j] = 1.f/(1.f + __expf(-h1a[j]));
        h1b[j] = 1.f/(1.f + __expf(-h1b[j]));
    }
    float h2a0 = sw[oB2+0], h2a1 = sw[oB2+1];
    float h2b0 = sw[F2+oB2+0], h2b1 = sw[F2+oB2+1];
    #pragma unroll
    for (int i = 0; i < 16; ++i) {
        h2a0 += h1a[i]*sw[oW2 + i*2 + 0];
        h2a1 += h1a[i]*sw[oW2 + i*2 + 1];
        h2b0 += h1b[i]*sw[F2+oW2 + i*2 + 0];
        h2b1 += h1b[i]*sw[F2+oW2 + i*2 + 1];
    }
    h2a0 = 1.f/(1.f + __expf(-h2a0)); h2a1 = 1.f/(1.f + __expf(-h2a1));
    h2b0 = 1.f/(1.f + __expf(-h2b0)); h2b1 = 1.f/(1.f + __expf(-h2b1));

    const float* pn0 = ne0 + b*TD;
    const float* pn1 = ne1 + b*TD;
    #pragma unroll
    for (int jq = 0; jq < 8; ++jq) {
        float4 ba  = *(const float4*)&sw[oB3 + jq*4];
        float4 wa0 = *(const float4*)&sw[oW3 + jq*4];
        float4 wa1 = *(const float4*)&sw[oW3 + 32 + jq*4];
        float4 bb2 = *(const float4*)&sw[F2+oB3 + jq*4];
        float4 wb0 = *(const float4*)&sw[F2+oW3 + jq*4];
        float4 wb1 = *(const float4*)&sw[F2+oW3 + 32 + jq*4];
        float4 n0 = *(const float4*)&pn0[jq*4];
        float4 n1 = *(const float4*)&pn1[jq*4];
        ushort4 u1, u2;
        u1.x = f2b(tanhf(n0.x*(ba.x + h2a0*wa0.x + h2a1*wa1.x)));
        u1.y = f2b(tanhf(n0.y*(ba.y + h2a0*wa0.y + h2a1*wa1.y)));
        u1.z = f2b(tanhf(n0.z*(ba.z + h2a0*wa0.z + h2a1*wa1.z)));
        u1.w = f2b(tanhf(n0.w*(ba.w + h2a0*wa0.w + h2a1*wa1.w)));
        u2.x = f2b(tanhf(n1.x*(bb2.x + h2b0*wb0.x + h2b1*wb1.x)));
        u2.y = f2b(tanhf(n1.y*(bb2.y + h2b0*wb0.y + h2b1*wb1.y)));
        u2.z = f2b(tanhf(n1.z*(bb2.z + h2b0*wb0.z + h2b1*wb1.z)));
        u2.w = f2b(tanhf(n1.w*(bb2.w + h2b0*wb0.w + h2b1*wb1.w)));
        *(ushort4*)&nv1b[(size_t)p*TD + jq*4] = u1;
        *(ushort4*)&nv2b[(size_t)p*TD + jq*4] = u2;
    }
}

// ---------------------------------------------------------------------------
// K_BC: build combined pool matrices, K-transposed, bf16:
//   BcT[c][k], c = d*O + o, k = (kp*66 + i), value = pool[d,kp,i,o]+pool[d,kp+2,i,o]
//   k in [132,160) zero-padded. gate cols 1280, upd cols 640.
// ---------------------------------------------------------------------------
__global__ __launch_bounds__(256) void k_bc(
    const float* __restrict__ gate_w, const float* __restrict__ upd_w,
    unsigned short* __restrict__ BcTg, unsigned short* __restrict__ BcTu)
{
    int tid = blockIdx.x*256 + threadIdx.x;       // < 1920*160
    int c = tid / KP, k = tid - c*KP;
    const float* pool; int O, cc; unsigned short* dst;
    if (c < 1280) { pool = gate_w; O = OG; cc = c;        dst = BcTg; }
    else          { pool = upd_w;  O = OU; cc = c - 1280; dst = BcTu; }
    int d = cc / O, o = cc - d*O;
    float v = 0.f;
    if (k < 132) {
        int kp = (k < 66) ? 0 : 1;
        int i  = (k < 66) ? k : k - 66;
        v = pool[(size_t)((d*4 + kp)*CIN + i)*O + o]
          + pool[(size_t)((d*4 + kp + 2)*CIN + i)*O + o];
    }
    dst[(size_t)cc*KP + k] = f2b(v);
}

// ---------------------------------------------------------------------------
// K_XT: build XTg[b][68][1024] bf16: rows 0-1 = x cols, 2-65 = state (MODE1:
// z*state), 66 = ones (rowsum trick), 67 = zeros. Transposed for MFMA B-frags.
// ---------------------------------------------------------------------------
template<int MODE>
__global__ __launch_bounds__(256) void k_xt(
    const float* __restrict__ x, const float* __restrict__ state,
    const float* __restrict__ zr, unsigned short* __restrict__ XTg)
{
    __shared__ unsigned short st[68*72];   // [c][m], m-stride 72
    int t = threadIdx.x;
    int b = blockIdx.y, m0 = blockIdx.x*64;
    for (int i = t; i < 1024; i += 256) {
        int m = i >> 4, cq = i & 15;
        size_t base = (size_t)b*NN + m0 + m;
        float4 v = *(const float4*)&state[base*DOUT + cq*4];
        if (MODE == 1) {
            float4 z = *(const float4*)&zr[base*OG + cq*4];
            v.x *= z.x; v.y *= z.y; v.z *= z.z; v.w *= z.w;
        }
        st[(2 + cq*4 + 0)*72 + m] = f2b(v.x);
        st[(2 + cq*4 + 1)*72 + m] = f2b(v.y);
        st[(2 + cq*4 + 2)*72 + m] = f2b(v.z);
        st[(2 + cq*4 + 3)*72 + m] = f2b(v.w);
    }
    if (t < 128) {
        int m = t >> 1, c = t & 1;
        st[c*72 + m] = f2b(x[((size_t)b*NN + m0 + m)*DIN + c]);
    }
    __syncthreads();
    const unsigned int ONE2 = 0x3F803F80u;
    for (int i = t; i < 68*8; i += 256) {
        int c = i >> 3, ch = i & 7;
        uint4 v;
        if (c < 66)      v = *(const uint4*)&st[c*72 + ch*8];
        else if (c == 66) v = make_uint4(ONE2, ONE2, ONE2, ONE2);
        else              v = make_uint4(0, 0, 0, 0);
        *(uint4*)&XTg[((size_t)b*68 + c)*1024 + m0 + ch*8] = v;
    }
}

// ---------------------------------------------------------------------------
// K3: fused A-apply via MFMA; epilogue emits the GEMM A-matrix row bf16:
//   A[row][0..65] = X, A[row][66..131] = (relu(adj)@X + X)/(1+rowsum), pad 0.
// ---------------------------------------------------------------------------
template<int MODE>
__global__ __launch_bounds__(256) void k_aapply(
    const unsigned short* __restrict__ nv1b, const unsigned short* __restrict__ nv2b,
    const unsigned short* __restrict__ XTg,
    const float* __restrict__ x, const float* __restrict__ state,
    const float* __restrict__ zr, unsigned short* __restrict__ A)
{
    __shared__ unsigned short s_nv1r[64*40], s_nv2r[64*40];
    __shared__ unsigned short s_nv1c[64*40], s_nv2c[64*40];
    __shared__ unsigned short s_p[64*72];
    __shared__ unsigned short s_xt[80*72];
    __shared__ float s_rs[64];

    int t = threadIdx.x;
    int b = blockIdx.y, rbase = blockIdx.x*64;
    int w = t >> 6, lane = t & 63, lq = lane >> 4, ln = lane & 15;

    for (int i = t; i < 512; i += 256) {
        int arr = i >> 8, j = i & 255;
        int node = j >> 2, ch = j & 3;
        const unsigned short* src = (arr ? nv2b : nv1b)
            + ((size_t)b*NN + rbase + node)*TD + ch*8;
        unsigned short* dst = (arr ? s_nv2r : s_nv1r) + node*40 + ch*8;
        *(uint4*)dst = *(const uint4*)src;
    }
    for (int i = t; i < 12*72; i += 256) s_xt[68*72 + i] = 0;
    __syncthreads();

    bf16x8 a1 = *(const bf16x8*)&s_nv1r[(16*w + ln)*40 + lq*8];
    s16x8 a2s = *(const s16x8*)&s_nv2r[(16*w + ln)*40 + lq*8];
    const s16x8 sgn = {(short)0x8000,(short)0x8000,(short)0x8000,(short)0x8000,
                       (short)0x8000,(short)0x8000,(short)0x8000,(short)0x8000};
    a2s ^= sgn;
    bf16x8 a2n = (bf16x8)a2s;

    f32x4 acc[5];
    #pragma unroll
    for (int i = 0; i < 5; ++i) acc[i] = (f32x4){0.f,0.f,0.f,0.f};
    const f32x4 zero4 = {0.f,0.f,0.f,0.f};

    for (int mb = 0; mb < NN; mb += 64) {
        __syncthreads();
        for (int i = t; i < 512; i += 256) {
            int arr = i >> 8, j = i & 255;
            int node = j >> 2, ch = j & 3;
            const unsigned short* src = (arr ? nv2b : nv1b)
                + ((size_t)b*NN + mb + node)*TD + ch*8;
            unsigned short* dst = (arr ? s_nv2c : s_nv1c) + node*40 + ch*8;
            *(uint4*)dst = *(const uint4*)src;
        }
        for (int i = t; i < 544; i += 256) {
            int c = i >> 3, ch = i & 7;
            *(uint4*)&s_xt[c*72 + ch*8] =
                *(const uint4*)&XTg[((size_t)b*68 + c)*1024 + mb + ch*8];
        }
        __syncthreads();

        #pragma unroll
        for (int j0t = 0; j0t < 4; ++j0t) {
            int j0 = j0t*16;
            bf16x8 b2 = *(const bf16x8*)&s_nv2c[(j0 + ln)*40 + lq*8];
            bf16x8 b1 = *(const bf16x8*)&s_nv1c[(j0 + ln)*40 + lq*8];
            f32x4 s = __builtin_amdgcn_mfma_f32_16x16x32_bf16(a1,  b2, zero4, 0, 0, 0);
            s       = __builtin_amdgcn_mfma_f32_16x16x32_bf16(a2n, b1, s,     0, 0, 0);
            #pragma unroll
            for (int r = 0; r < 4; ++r) {
                float p = fmaxf(s[r], 0.f);
                *(__bf16*)&s_p[(16*w + lq*4 + r)*72 + j0 + ln] = (__bf16)p;
            }
        }

        bf16x8 pa0 = *(const bf16x8*)&s_p[(16*w + ln)*72 +      lq*8];
        bf16x8 pa1 = *(const bf16x8*)&s_p[(16*w + ln)*72 + 32 + lq*8];
        #pragma unroll
        for (int n0t = 0; n0t < 5; ++n0t) {
            int n0 = n0t*16;
            bf16x8 xb0 = *(const bf16x8*)&s_xt[(n0 + ln)*72 +      lq*8];
            bf16x8 xb1 = *(const bf16x8*)&s_xt[(n0 + ln)*72 + 32 + lq*8];
            acc[n0t] = __builtin_amdgcn_mfma_f32_16x16x32_bf16(pa0, xb0, acc[n0t], 0, 0, 0);
            acc[n0t] = __builtin_amdgcn_mfma_f32_16x16x32_bf16(pa1, xb1, acc[n0t], 0, 0, 0);
        }
    }

    if (ln == 2) {
        #pragma unroll
        for (int r = 0; r < 4; ++r) s_rs[16*w + lq*4 + r] = acc[4][r];
    }
    float rinv[4];
    #pragma unroll
    for (int r = 0; r < 4; ++r) rinv[r] = 1.0f / (1.0f + s_rs[16*w + lq*4 + r]);

    #pragma unroll
    for (int n0t = 0; n0t < 5; ++n0t) {
        int c = n0t*16 + ln;
        if (c < CIN) {
            #pragma unroll
            for (int r = 0; r < 4; ++r) {
                int gr = rbase + 16*w + lq*4 + r;
                size_t rowG = (size_t)b*NN + gr;
                float xr = loadX<MODE>(x, state, zr, b, gr, c);
                A[rowG*KP + c]      = f2b(xr);
                A[rowG*KP + 66 + c] = f2b((acc[n0t][r] + xr) * rinv[r]);
            }
        }
    }
    // zero-pad K cols 132..159
    for (int i = t; i < 64*28; i += 256) {
        int rr = i / 28, cc = 132 + (i - 28*(i/28));
        A[((size_t)b*NN + rbase + rr)*KP + cc] = 0;
    }
}

// ---------------------------------------------------------------------------
// K_GEMM: G = A @ BcT^T with in-register d-contraction epilogue.
//   Block: 64 rows x 160 cols (10 d x 16 o).  C-tile ct == d.
//   MODE 0 (gate): zr[row][o0+ln] = sigmoid(sum_d ne2*(acc_d + bias_d))
//   MODE 1 (upd):  out = r*state + (1-r)*tanh(...)
// ---------------------------------------------------------------------------
template<int O, int MODE>
__global__ __launch_bounds__(256) void k_gemm(
    const unsigned short* __restrict__ A, const unsigned short* __restrict__ BcT,
    const float* __restrict__ ne2, const float* __restrict__ bias_pool,
    const float* __restrict__ state, float* __restrict__ zr,
    float* __restrict__ out)
{
    __shared__ unsigned short s_a[64*168];     // [row][k], stride 168
    __shared__ unsigned short s_b[160*168];    // [cc=d*16+oo][k]
    __shared__ float s_ne[64*ED];
    __shared__ float s_bias[160];

    int t = threadIdx.x;
    int w = t >> 6, lane = t & 63, lq = lane >> 4, ln = lane & 15;
    int rowStart = blockIdx.x*64;
    int o0 = blockIdx.y*16;

    for (int i = t; i < 1280; i += 256) {      // A: 64 rows x 20 chunks
        int r = i / 20, kc = i - r*20;
        *(uint4*)&s_a[r*168 + kc*8] =
            *(const uint4*)&A[(size_t)(rowStart + r)*KP + kc*8];
    }
    for (int i = t; i < 3200; i += 256) {      // B: 160 cols x 20 chunks
        int cc = i / 20, kc = i - cc*20;
        int d = cc >> 4, oo = cc & 15;
        *(uint4*)&s_b[cc*168 + kc*8] =
            *(const uint4*)&BcT[(size_t)(d*O + o0 + oo)*KP + kc*8];
    }
    int nbase = rowStart & (NN-1);
    for (int i = t; i < 64*ED; i += 256) {
        int r = i / ED, d = i - r*ED;
        s_ne[i] = ne2[(size_t)(nbase + r)*ED + d];
    }
    if (t < 160) {
        int d = t >> 4, oo = t & 15;
        s_bias[t] = bias_pool[(size_t)d*O + o0 + oo];
    }
    __syncthreads();

    f32x4 acc[10];
    #pragma unroll
    for (int i = 0; i < 10; ++i) acc[i] = (f32x4){0.f,0.f,0.f,0.f};

    #pragma unroll
    for (int kc = 0; kc < 5; ++kc) {
        bf16x8 af = *(const bf16x8*)&s_a[(16*w + ln)*168 + kc*32 + lq*8];
        #pragma unroll
        for (int ct = 0; ct < 10; ++ct) {
            bf16x8 bf = *(const bf16x8*)&s_b[(ct*16 + ln)*168 + kc*32 + lq*8];
            acc[ct] = __builtin_amdgcn_mfma_f32_16x16x32_bf16(af, bf, acc[ct], 0, 0, 0);
        }
    }

    int o = o0 + ln;
    #pragma unroll
    for (int r = 0; r < 4; ++r) {
        int row_l = 16*w + lq*4 + r;
        size_t rowG = (size_t)rowStart + row_l;
        float val = 0.f;
        #pragma unroll
        for (int d = 0; d < ED; ++d)
            val += s_ne[row_l*ED + d] * (acc[d][r] + s_bias[d*16 + ln]);
        if (MODE == 0) {
            zr[rowG*OG + o] = 1.f/(1.f + __expf(-val));
        } else {
            float hc = tanhf(val);
            float st = state[rowG*OU + o];
            float rg = zr[rowG*OG + OU + o];
            out[rowG*OU + o] = rg*st + (1.f - rg)*hc;
        }
    }
}

// ---------------------------------------------------------------------------
extern "C" void kernel_launch(void* const* d_in, const int* in_sizes, int n_in,
                              void* d_out, int out_size, void* d_ws, size_t ws_size,
                              hipStream_t stream)
{
    const float* x      = (const float*)d_in[0];
    const float* state  = (const float*)d_in[1];
    const float* ne0    = (const float*)d_in[2];
    const float* ne1    = (const float*)d_in[3];
    const float* ne2    = (const float*)d_in[4];
    const float* f1w1   = (const float*)d_in[5];
    const float* f1b1   = (const float*)d_in[6];
    const float* f1w2   = (const float*)d_in[7];
    const float* f1b2   = (const float*)d_in[8];
    const float* f1w3   = (const float*)d_in[9];
    const float* f1b3   = (const float*)d_in[10];
    const float* f2w1   = (const float*)d_in[11];
    const float* f2b1   = (const float*)d_in[12];
    const float* f2w2   = (const float*)d_in[13];
    const float* f2b2   = (const float*)d_in[14];
    const float* f2w3   = (const float*)d_in[15];
    const float* f2b3   = (const float*)d_in[16];
    const float* gate_w = (const float*)d_in[17];
    const float* gate_b = (const float*)d_in[18];
    const float* upd_w  = (const float*)d_in[19];
    const float* upd_b  = (const float*)d_in[20];

    // ws: nv1b 2M | nv2b 2M | XTg 4.45M | A 10.5M | BcTg 0.41M | BcTu 0.2M | zr 16M
    unsigned short* nv1b = (unsigned short*)d_ws;
    unsigned short* nv2b = nv1b + (size_t)BB*NN*TD;
    unsigned short* XTg  = nv2b + (size_t)BB*NN*TD;
    unsigned short* A    = XTg  + (size_t)BB*68*NN;
    unsigned short* BcTg = A    + (size_t)BB*NN*KP;
    unsigned short* BcTu = BcTg + (size_t)1280*KP;
    float* zr = (float*)(BcTu + (size_t)640*KP);
    float* out = (float*)d_out;

    k_nv<<<dim3(BB*NN/256), 256, 0, stream>>>(x, state, ne0, ne1,
        f1w1, f1b1, f1w2, f1b2, f1w3, f1b3,
        f2w1, f2b1, f2w2, f2b2, f2w3, f2b3, nv1b, nv2b);

    k_bc<<<dim3(1920*KP/256), 256, 0, stream>>>(gate_w, upd_w, BcTg, BcTu);

    k_xt<0><<<dim3(NN/64, BB), 256, 0, stream>>>(x, state, nullptr, XTg);

    k_aapply<0><<<dim3(NN/64, BB), 256, 0, stream>>>(nv1b, nv2b, XTg,
                                                     x, state, nullptr, A);

    k_gemm<OG,0><<<dim3(BB*NN/64, 8), 256, 0, stream>>>(A, BcTg, ne2, gate_b,
                                                        nullptr, zr, nullptr);

    k_xt<1><<<dim3(NN/64, BB), 256, 0, stream>>>(x, state, zr, XTg);

    k_aapply<1><<<dim3(NN/64, BB), 256, 0, stream>>>(nv1b, nv2b, XTg,
                                                     x, state, zr, A);

    k_gemm<OU,1><<<dim3(BB*NN/64, 4), 256, 0, stream>>>(A, BcTu, ne2, upd_b,
                                                        state, zr, out);
}

// Round 4
// 305.451 us; speedup vs baseline: 4.6764x; 1.0379x over previous
//
#include <hip/hip_runtime.h>
#include <math.h>

#define BB   32      // batch
#define NN   1024    // nodes
#define DIN  2
#define DOUT 64
#define CIN  66      // DIN + DOUT
#define TD   32
#define ED   10
#define OG   128     // 2*DOUT (gate out)
#define OU   64      // upd out
#define KP   160     // padded K for the einsum GEMM (132 real)

typedef __bf16 bf16x8 __attribute__((ext_vector_type(8)));
typedef float  f32x4  __attribute__((ext_vector_type(4)));
typedef short  s16x8  __attribute__((ext_vector_type(8)));

__device__ __forceinline__ unsigned short f2b(float f) {
    __bf16 h = (__bf16)f;
    return *(unsigned short*)&h;
}

// ---------------------------------------------------------------------------
template<int MODE>
__device__ __forceinline__ float loadX(const float* __restrict__ x,
                                       const float* __restrict__ state,
                                       const float* __restrict__ zr,
                                       int b, int m, int c)
{
    if (c < DIN) return x[((size_t)b*NN + m)*DIN + c];
    int j = c - DIN;
    float s = state[((size_t)b*NN + m)*DOUT + j];
    if (MODE == 1) s *= zr[((size_t)b*NN + m)*OG + j];
    return s;
}

// ---------------------------------------------------------------------------
// K1: tiny MLPs -> nv1, nv2 (bf16 out). One thread per (b,n).
// ---------------------------------------------------------------------------
__global__ __launch_bounds__(256) void k_nv(
    const float* __restrict__ x, const float* __restrict__ state,
    const float* __restrict__ ne0, const float* __restrict__ ne1,
    const float* __restrict__ w11, const float* __restrict__ b11,
    const float* __restrict__ w12, const float* __restrict__ b12,
    const float* __restrict__ w13, const float* __restrict__ b13,
    const float* __restrict__ w21, const float* __restrict__ b21,
    const float* __restrict__ w22, const float* __restrict__ b22,
    const float* __restrict__ w23, const float* __restrict__ b23,
    unsigned short* __restrict__ nv1b, unsigned short* __restrict__ nv2b)
{
    const int oW1 = 0, oB1 = 1056, oW2 = 1072, oB2 = 1104, oW3 = 1108, oB3 = 1172, F2 = 1204;
    __shared__ float sw[2408];
    int t = threadIdx.x;
    for (int i = t; i < 1056; i += 256) { sw[oW1+i] = w11[i]; sw[F2+oW1+i] = w21[i]; }
    if (t < 16) { sw[oB1+t] = b11[t]; sw[F2+oB1+t] = b21[t]; }
    if (t < 32) { sw[oW2+t] = w12[t]; sw[F2+oW2+t] = w22[t]; }
    if (t < 2)  { sw[oB2+t] = b12[t]; sw[F2+oB2+t] = b22[t]; }
    if (t < 64) { sw[oW3+t] = w13[t]; sw[F2+oW3+t] = w23[t]; }
    if (t >= 64 && t < 96) { sw[oB3+t-64] = b13[t-64]; sw[F2+oB3+t-64] = b23[t-64]; }
    __syncthreads();

    int p = blockIdx.x*256 + t;
    int b = p >> 10;

    float h1a[16], h1b[16];
    #pragma unroll
    for (int j = 0; j < 16; ++j) { h1a[j] = sw[oB1+j]; h1b[j] = sw[F2+oB1+j]; }
    for (int i = 0; i < CIN; ++i) {
        float v = (i < DIN) ? x[(size_t)p*DIN + i] : state[(size_t)p*DOUT + (i-DIN)];
        #pragma unroll
        for (int jq = 0; jq < 4; ++jq) {
            float4 wa = *(const float4*)&sw[oW1 + i*16 + jq*4];
            float4 wb = *(const float4*)&sw[F2 + oW1 + i*16 + jq*4];
            h1a[jq*4+0] += v*wa.x; h1a[jq*4+1] += v*wa.y;
            h1a[jq*4+2] += v*wa.z; h1a[jq*4+3] += v*wa.w;
            h1b[jq*4+0] += v*wb.x; h1b[jq*4+1] += v*wb.y;
            h1b[jq*4+2] += v*wb.z; h1b[jq*4+3] += v*wb.w;
        }
    }
    #pragma unroll
    for (int j = 0; j < 16; ++j) {
        h1a[j] = 1.f/(1.f + __expf(-h1a[j]));
        h1b[j] = 1.f/(1.f + __expf(-h1b[j]));
    }
    float h2a0 = sw[oB2+0], h2a1 = sw[oB2+1];
    float h2b0 = sw[F2+oB2+0], h2b1 = sw[F2+oB2+1];
    #pragma unroll
    for (int i = 0; i < 16; ++i) {
        h2a0 += h1a[i]*sw[oW2 + i*2 + 0];
        h2a1 += h1a[i]*sw[oW2 + i*2 + 1];
        h2b0 += h1b[i]*sw[F2+oW2 + i*2 + 0];
        h2b1 += h1b[i]*sw[F2+oW2 + i*2 + 1];
    }
    h2a0 = 1.f/(1.f + __expf(-h2a0)); h2a1 = 1.f/(1.f + __expf(-h2a1));
    h2b0 = 1.f/(1.f + __expf(-h2b0)); h2b1 = 1.f/(1.f + __expf(-h2b1));

    const float* pn0 = ne0 + b*TD;
    const float* pn1 = ne1 + b*TD;
    #pragma unroll
    for (int jq = 0; jq < 8; ++jq) {
        float4 ba  = *(const float4*)&sw[oB3 + jq*4];
        float4 wa0 = *(const float4*)&sw[oW3 + jq*4];
        float4 wa1 = *(const float4*)&sw[oW3 + 32 + jq*4];
        float4 bb2 = *(const float4*)&sw[F2+oB3 + jq*4];
        float4 wb0 = *(const float4*)&sw[F2+oW3 + jq*4];
        float4 wb1 = *(const float4*)&sw[F2+oW3 + 32 + jq*4];
        float4 n0 = *(const float4*)&pn0[jq*4];
        float4 n1 = *(const float4*)&pn1[jq*4];
        ushort4 u1, u2;
        u1.x = f2b(tanhf(n0.x*(ba.x + h2a0*wa0.x + h2a1*wa1.x)));
        u1.y = f2b(tanhf(n0.y*(ba.y + h2a0*wa0.y + h2a1*wa1.y)));
        u1.z = f2b(tanhf(n0.z*(ba.z + h2a0*wa0.z + h2a1*wa1.z)));
        u1.w = f2b(tanhf(n0.w*(ba.w + h2a0*wa0.w + h2a1*wa1.w)));
        u2.x = f2b(tanhf(n1.x*(bb2.x + h2b0*wb0.x + h2b1*wb1.x)));
        u2.y = f2b(tanhf(n1.y*(bb2.y + h2b0*wb0.y + h2b1*wb1.y)));
        u2.z = f2b(tanhf(n1.z*(bb2.z + h2b0*wb0.z + h2b1*wb1.z)));
        u2.w = f2b(tanhf(n1.w*(bb2.w + h2b0*wb0.w + h2b1*wb1.w)));
        *(ushort4*)&nv1b[(size_t)p*TD + jq*4] = u1;
        *(ushort4*)&nv2b[(size_t)p*TD + jq*4] = u2;
    }
}

// ---------------------------------------------------------------------------
// K_BC: combined pool matrices, K-transposed, bf16.
// ---------------------------------------------------------------------------
__global__ __launch_bounds__(256) void k_bc(
    const float* __restrict__ gate_w, const float* __restrict__ upd_w,
    unsigned short* __restrict__ BcTg, unsigned short* __restrict__ BcTu)
{
    int tid = blockIdx.x*256 + threadIdx.x;       // < 1920*160
    int c = tid / KP, k = tid - c*KP;
    const float* pool; int O, cc; unsigned short* dst;
    if (c < 1280) { pool = gate_w; O = OG; cc = c;        dst = BcTg; }
    else          { pool = upd_w;  O = OU; cc = c - 1280; dst = BcTu; }
    int d = cc / O, o = cc - d*O;
    float v = 0.f;
    if (k < 132) {
        int kp = (k < 66) ? 0 : 1;
        int i  = (k < 66) ? k : k - 66;
        v = pool[(size_t)((d*4 + kp)*CIN + i)*O + o]
          + pool[(size_t)((d*4 + kp + 2)*CIN + i)*O + o];
    }
    dst[(size_t)cc*KP + k] = f2b(v);
}

// ---------------------------------------------------------------------------
// K_XT: XTg[b][68][1024] bf16 (rows 0-1 x, 2-65 state/z*state, 66 ones, 67 0).
// ---------------------------------------------------------------------------
template<int MODE>
__global__ __launch_bounds__(256) void k_xt(
    const float* __restrict__ x, const float* __restrict__ state,
    const float* __restrict__ zr, unsigned short* __restrict__ XTg)
{
    __shared__ unsigned short st[68*72];
    int t = threadIdx.x;
    int b = blockIdx.y, m0 = blockIdx.x*64;
    for (int i = t; i < 1024; i += 256) {
        int m = i >> 4, cq = i & 15;
        size_t base = (size_t)b*NN + m0 + m;
        float4 v = *(const float4*)&state[base*DOUT + cq*4];
        if (MODE == 1) {
            float4 z = *(const float4*)&zr[base*OG + cq*4];
            v.x *= z.x; v.y *= z.y; v.z *= z.z; v.w *= z.w;
        }
        st[(2 + cq*4 + 0)*72 + m] = f2b(v.x);
        st[(2 + cq*4 + 1)*72 + m] = f2b(v.y);
        st[(2 + cq*4 + 2)*72 + m] = f2b(v.z);
        st[(2 + cq*4 + 3)*72 + m] = f2b(v.w);
    }
    if (t < 128) {
        int m = t >> 1, c = t & 1;
        st[c*72 + m] = f2b(x[((size_t)b*NN + m0 + m)*DIN + c]);
    }
    __syncthreads();
    const unsigned int ONE2 = 0x3F803F80u;
    for (int i = t; i < 68*8; i += 256) {
        int c = i >> 3, ch = i & 7;
        uint4 v;
        if (c < 66)      v = *(const uint4*)&st[c*72 + ch*8];
        else if (c == 66) v = make_uint4(ONE2, ONE2, ONE2, ONE2);
        else              v = make_uint4(0, 0, 0, 0);
        *(uint4*)&XTg[((size_t)b*68 + c)*1024 + m0 + ch*8] = v;
    }
}

// ---------------------------------------------------------------------------
// K3: fused A-apply via MFMA; double-buffered col staging, 1 barrier/iter.
// Epilogue emits GEMM A-matrix rows bf16: [X | (relu(adj)@X+X)/(1+rs) | 0pad].
// ---------------------------------------------------------------------------
template<int MODE>
__global__ __launch_bounds__(256) void k_aapply(
    const unsigned short* __restrict__ nv1b, const unsigned short* __restrict__ nv2b,
    const unsigned short* __restrict__ XTg,
    const float* __restrict__ x, const float* __restrict__ state,
    const float* __restrict__ zr, unsigned short* __restrict__ A)
{
    __shared__ unsigned short s_nv1r[64*40], s_nv2r[64*40];   // 10.2 KB
    __shared__ unsigned short s_nvc[2][2][64*40];             // 20.5 KB (db)
    __shared__ unsigned short s_p[64*72];                     //  9.2 KB
    __shared__ unsigned short s_xt[2][80*72];                 // 23.0 KB (db)
    __shared__ float s_rs[64];

    int t = threadIdx.x;
    int b = blockIdx.y, rbase = blockIdx.x*64;
    int w = t >> 6, lane = t & 63, lq = lane >> 4, ln = lane & 15;

    // prolog: row-nv, xt pads, tile-0 staging into buf 0
    for (int i = t; i < 512; i += 256) {
        int arr = i >> 8, j = i & 255;
        int node = j >> 2, ch = j & 3;
        const unsigned short* src = (arr ? nv2b : nv1b)
            + ((size_t)b*NN + rbase + node)*TD + ch*8;
        unsigned short* dst = (arr ? s_nv2r : s_nv1r) + node*40 + ch*8;
        *(uint4*)dst = *(const uint4*)src;
    }
    for (int i = t; i < 12*72; i += 256) {     // zero pad rows 68..79 both bufs
        s_xt[0][68*72 + i] = 0; s_xt[1][68*72 + i] = 0;
    }
    for (int i = t; i < 512; i += 256) {       // tile 0 col-nv
        int arr = i >> 8, j = i & 255;
        int node = j >> 2, ch = j & 3;
        const unsigned short* src = (arr ? nv2b : nv1b)
            + ((size_t)b*NN + node)*TD + ch*8;
        *(uint4*)&s_nvc[0][arr][node*40 + ch*8] = *(const uint4*)src;
    }
    for (int i = t; i < 544; i += 256) {       // tile 0 xt
        int c = i >> 3, ch = i & 7;
        *(uint4*)&s_xt[0][c*72 + ch*8] =
            *(const uint4*)&XTg[((size_t)b*68 + c)*1024 + ch*8];
    }
    __syncthreads();

    bf16x8 a1 = *(const bf16x8*)&s_nv1r[(16*w + ln)*40 + lq*8];
    s16x8 a2s = *(const s16x8*)&s_nv2r[(16*w + ln)*40 + lq*8];
    const s16x8 sgn = {(short)0x8000,(short)0x8000,(short)0x8000,(short)0x8000,
                       (short)0x8000,(short)0x8000,(short)0x8000,(short)0x8000};
    a2s ^= sgn;
    bf16x8 a2n = (bf16x8)a2s;

    f32x4 acc[5];
    #pragma unroll
    for (int i = 0; i < 5; ++i) acc[i] = (f32x4){0.f,0.f,0.f,0.f};
    const f32x4 zero4 = {0.f,0.f,0.f,0.f};

    for (int it = 0; it < 16; ++it) {
        int buf = it & 1;
        bool pre = (it < 15);
        int mbn = (it + 1) * 64;

        // issue next-tile global loads (registers; writes after compute)
        uint4 cnv[2]; uint4 xtv[3]; int xcnt = 0;
        if (pre) {
            #pragma unroll
            for (int j = 0; j < 2; ++j) {
                int i = t + j*256;
                int arr = i >> 8, jj = i & 255;
                int node = jj >> 2, ch = jj & 3;
                cnv[j] = *(const uint4*)((arr ? nv2b : nv1b)
                         + ((size_t)b*NN + mbn + node)*TD + ch*8);
            }
            #pragma unroll
            for (int j = 0; j < 3; ++j) {
                int i = t + j*256;
                if (i < 544) {
                    int c = i >> 3, ch = i & 7;
                    xtv[j] = *(const uint4*)&XTg[((size_t)b*68 + c)*1024 + mbn + ch*8];
                    xcnt = j + 1;
                }
            }
        }

        // ---- S phase
        #pragma unroll
        for (int j0t = 0; j0t < 4; ++j0t) {
            int j0 = j0t*16;
            bf16x8 b2 = *(const bf16x8*)&s_nvc[buf][1][(j0 + ln)*40 + lq*8];
            bf16x8 b1 = *(const bf16x8*)&s_nvc[buf][0][(j0 + ln)*40 + lq*8];
            f32x4 s = __builtin_amdgcn_mfma_f32_16x16x32_bf16(a1,  b2, zero4, 0, 0, 0);
            s       = __builtin_amdgcn_mfma_f32_16x16x32_bf16(a2n, b1, s,     0, 0, 0);
            #pragma unroll
            for (int r = 0; r < 4; ++r) {
                float p = fmaxf(s[r], 0.f);
                *(__bf16*)&s_p[(16*w + lq*4 + r)*72 + j0 + ln] = (__bf16)p;
            }
        }

        // ---- PV phase
        bf16x8 pa0 = *(const bf16x8*)&s_p[(16*w + ln)*72 +      lq*8];
        bf16x8 pa1 = *(const bf16x8*)&s_p[(16*w + ln)*72 + 32 + lq*8];
        #pragma unroll
        for (int n0t = 0; n0t < 5; ++n0t) {
            int n0 = n0t*16;
            bf16x8 xb0 = *(const bf16x8*)&s_xt[buf][(n0 + ln)*72 +      lq*8];
            bf16x8 xb1 = *(const bf16x8*)&s_xt[buf][(n0 + ln)*72 + 32 + lq*8];
            acc[n0t] = __builtin_amdgcn_mfma_f32_16x16x32_bf16(pa0, xb0, acc[n0t], 0, 0, 0);
            acc[n0t] = __builtin_amdgcn_mfma_f32_16x16x32_bf16(pa1, xb1, acc[n0t], 0, 0, 0);
        }

        // ---- write staged next tile into other buffer, then barrier
        if (pre) {
            int nbuf = buf ^ 1;
            #pragma unroll
            for (int j = 0; j < 2; ++j) {
                int i = t + j*256;
                int arr = i >> 8, jj = i & 255;
                int node = jj >> 2, ch = jj & 3;
                *(uint4*)&s_nvc[nbuf][arr][node*40 + ch*8] = cnv[j];
            }
            #pragma unroll
            for (int j = 0; j < 3; ++j) {
                int i = t + j*256;
                if (j < xcnt) {
                    int c = i >> 3, ch = i & 7;
                    *(uint4*)&s_xt[nbuf][c*72 + ch*8] = xtv[j];
                }
            }
            __syncthreads();
        }
    }

    if (ln == 2) {
        #pragma unroll
        for (int r = 0; r < 4; ++r) s_rs[16*w + lq*4 + r] = acc[4][r];
    }
    float rinv[4];
    #pragma unroll
    for (int r = 0; r < 4; ++r) rinv[r] = 1.0f / (1.0f + s_rs[16*w + lq*4 + r]);

    #pragma unroll
    for (int n0t = 0; n0t < 5; ++n0t) {
        int c = n0t*16 + ln;
        if (c < CIN) {
            #pragma unroll
            for (int r = 0; r < 4; ++r) {
                int gr = rbase + 16*w + lq*4 + r;
                size_t rowG = (size_t)b*NN + gr;
                float xr = loadX<MODE>(x, state, zr, b, gr, c);
                A[rowG*KP + c]      = f2b(xr);
                A[rowG*KP + 66 + c] = f2b((acc[n0t][r] + xr) * rinv[r]);
            }
        }
    }
    for (int i = t; i < 64*28; i += 256) {
        int rr = i / 28, cc = 132 + (i - 28*(i/28));
        A[((size_t)b*NN + rbase + rr)*KP + cc] = 0;
    }
}

// ---------------------------------------------------------------------------
// K_GEMM v2: B-resident block, loops NT row-tiles of 64.
//   slice = 16 o's -> 160 cc (10 d x 16 o); C-tile ct == d; in-register
//   d-contraction epilogue fused with sigmoid (gate) / tanh+GRU (upd).
// ---------------------------------------------------------------------------
template<int O, int MODE, int NT>
__global__ __launch_bounds__(256) void k_gemm(
    const unsigned short* __restrict__ A, const unsigned short* __restrict__ BcT,
    const float* __restrict__ ne2, const float* __restrict__ bias_pool,
    const float* __restrict__ state, float* __restrict__ zr,
    float* __restrict__ out)
{
    __shared__ unsigned short s_b[160*168];    // 53.8 KB, resident all tiles
    __shared__ unsigned short s_a[64*168];     // 21.5 KB, per tile
    __shared__ float s_ne[64*ED];
    __shared__ float s_bias[160];

    int t = threadIdx.x;
    int w = t >> 6, lane = t & 63, lq = lane >> 4, ln = lane & 15;
    int o0 = blockIdx.y*16;

    for (int i = t; i < 3200; i += 256) {      // stage B once
        int cc = i / 20, kc = i - cc*20;
        int d = cc >> 4, oo = cc & 15;
        *(uint4*)&s_b[cc*168 + kc*8] =
            *(const uint4*)&BcT[(size_t)(d*O + o0 + oo)*KP + kc*8];
    }
    if (t < 160) {
        int d = t >> 4, oo = t & 15;
        s_bias[t] = bias_pool[(size_t)d*O + o0 + oo];
    }

    for (int tile = 0; tile < NT; ++tile) {
        int rowStart = (blockIdx.x*NT + tile)*64;
        __syncthreads();                        // s_a/s_ne safe to overwrite
        for (int i = t; i < 1280; i += 256) {
            int r = i / 20, kc = i - r*20;
            *(uint4*)&s_a[r*168 + kc*8] =
                *(const uint4*)&A[(size_t)(rowStart + r)*KP + kc*8];
        }
        int nb = rowStart & (NN-1);
        for (int i = t; i < 64*ED; i += 256) {
            int r = i / ED, d = i - r*ED;
            s_ne[i] = ne2[(size_t)(nb + r)*ED + d];
        }
        __syncthreads();

        f32x4 acc[10];
        #pragma unroll
        for (int i = 0; i < 10; ++i) acc[i] = (f32x4){0.f,0.f,0.f,0.f};

        #pragma unroll
        for (int kc = 0; kc < 5; ++kc) {
            bf16x8 af = *(const bf16x8*)&s_a[(16*w + ln)*168 + kc*32 + lq*8];
            #pragma unroll
            for (int ct = 0; ct < 10; ++ct) {
                bf16x8 bf = *(const bf16x8*)&s_b[(ct*16 + ln)*168 + kc*32 + lq*8];
                acc[ct] = __builtin_amdgcn_mfma_f32_16x16x32_bf16(af, bf, acc[ct], 0, 0, 0);
            }
        }

        int o = o0 + ln;
        #pragma unroll
        for (int r = 0; r < 4; ++r) {
            int row_l = 16*w + lq*4 + r;
            size_t rowG = (size_t)rowStart + row_l;
            float val = 0.f;
            #pragma unroll
            for (int d = 0; d < ED; ++d)
                val += s_ne[row_l*ED + d] * (acc[d][r] + s_bias[d*16 + ln]);
            if (MODE == 0) {
                zr[rowG*OG + o] = 1.f/(1.f + __expf(-val));
            } else {
                float hc = tanhf(val);
                float st = state[rowG*OU + o];
                float rg = zr[rowG*OG + OU + o];
                out[rowG*OU + o] = rg*st + (1.f - rg)*hc;
            }
        }
    }
}

// ---------------------------------------------------------------------------
extern "C" void kernel_launch(void* const* d_in, const int* in_sizes, int n_in,
                              void* d_out, int out_size, void* d_ws, size_t ws_size,
                              hipStream_t stream)
{
    const float* x      = (const float*)d_in[0];
    const float* state  = (const float*)d_in[1];
    const float* ne0    = (const float*)d_in[2];
    const float* ne1    = (const float*)d_in[3];
    const float* ne2    = (const float*)d_in[4];
    const float* f1w1   = (const float*)d_in[5];
    const float* f1b1   = (const float*)d_in[6];
    const float* f1w2   = (const float*)d_in[7];
    const float* f1b2   = (const float*)d_in[8];
    const float* f1w3   = (const float*)d_in[9];
    const float* f1b3   = (const float*)d_in[10];
    const float* f2w1   = (const float*)d_in[11];
    const float* f2b1   = (const float*)d_in[12];
    const float* f2w2   = (const float*)d_in[13];
    const float* f2b2   = (const float*)d_in[14];
    const float* f2w3   = (const float*)d_in[15];
    const float* f2b3   = (const float*)d_in[16];
    const float* gate_w = (const float*)d_in[17];
    const float* gate_b = (const float*)d_in[18];
    const float* upd_w  = (const float*)d_in[19];
    const float* upd_b  = (const float*)d_in[20];

    unsigned short* nv1b = (unsigned short*)d_ws;
    unsigned short* nv2b = nv1b + (size_t)BB*NN*TD;
    unsigned short* XTg  = nv2b + (size_t)BB*NN*TD;
    unsigned short* A    = XTg  + (size_t)BB*68*NN;
    unsigned short* BcTg = A    + (size_t)BB*NN*KP;
    unsigned short* BcTu = BcTg + (size_t)1280*KP;
    float* zr = (float*)(BcTu + (size_t)640*KP);
    float* out = (float*)d_out;

    k_nv<<<dim3(BB*NN/256), 256, 0, stream>>>(x, state, ne0, ne1,
        f1w1, f1b1, f1w2, f1b2, f1w3, f1b3,
        f2w1, f2b1, f2w2, f2b2, f2w3, f2b3, nv1b, nv2b);

    k_bc<<<dim3(1920*KP/256), 256, 0, stream>>>(gate_w, upd_w, BcTg, BcTu);

    k_xt<0><<<dim3(NN/64, BB), 256, 0, stream>>>(x, state, nullptr, XTg);

    k_aapply<0><<<dim3(NN/64, BB), 256, 0, stream>>>(nv1b, nv2b, XTg,
                                                     x, state, nullptr, A);

    k_gemm<OG,0,4><<<dim3(BB*NN/64/4, 8), 256, 0, stream>>>(A, BcTg, ne2, gate_b,
                                                            nullptr, zr, nullptr);

    k_xt<1><<<dim3(NN/64, BB), 256, 0, stream>>>(x, state, zr, XTg);

    k_aapply<1><<<dim3(NN/64, BB), 256, 0, stream>>>(nv1b, nv2b, XTg,
                                                     x, state, zr, A);

    k_gemm<OU,1,4><<<dim3(BB*NN/64/4, 4), 256, 0, stream>>>(A, BcTu, ne2, upd_b,
                                                            state, zr, out);
}